// Round 25
// baseline (153.999 us; speedup 1.0000x reference)
//
#include <hip/hip_runtime.h>
#include <stdint.h>

#define N_DET 20000
#define N_CLS 80
#define NELEM (N_DET * N_CLS)
#define TOPK  1000
#define CONF  0.05f
#define CANDS 1280
#define SORTN 2048
#define FASTN 256
#define NBLK  128  // blocks for hist/count/place passes (3125 float4 each)

typedef unsigned long long u64;
typedef unsigned int u32;

// Exact replication of RN(inter/denom) > 0.5 without fdiv:
// RN(a/b) > 0.5  <=>  a/b > 0.5 + 2^-25 (tie rounds-to-even to 0.5)
//               <=>  a * 2^25 > b * (2^24 + 1), both products exact in f64.
__device__ __forceinline__ bool iou_gt_half(float4 bi, float ai,
                                            float4 bj, float aj) {
  #pragma clang fp contract(off)
  float iw = fmaxf(fminf(bi.z, bj.z) - fmaxf(bi.x, bj.x), 0.0f);
  float ih = fmaxf(fminf(bi.w, bj.w) - fmaxf(bi.y, bj.y), 0.0f);
  float inter = iw * ih;
  float denom = ai + aj - inter + 1e-9f;
  return (double)inter * 33554432.0 > (double)denom * 16777217.0;
}

// ---------------------------------------------------------------------------
// Workspace layout (total 1,706,240 B - NO overlaps):
//   T16 @0 (320) | T160 @320 (320) | cnt @960 (320)
//   cls_out @641280 (40960)   [fully written each call]
//   ghistA @682240 (40960) | ghistB @723200 (81920)   [zeroed by k_zero]
//   cand @805120 (819200) | bcnt @1624320 (40960)
// ---------------------------------------------------------------------------
#define OFF_T16    0
#define OFF_T160   320
#define OFF_CNT    960
#define OFF_CLSOUT 641280
#define OFF_GHA    682240
#define OFF_GHB    723200
#define OFF_CAND   805120
#define OFF_BCNT   1624320

// Zero ghistA+ghistB (contiguous 122880 B = 7680 uint4).
__global__ __launch_bounds__(256) void k_zero(u32* __restrict__ gh) {
  uint4 z4 = make_uint4(0u, 0u, 0u, 0u);
  uint4* p = (uint4*)gh;
  int i = blockIdx.x * 256 + threadIdx.x;
  if (i < 7680) p[i] = z4;
}

// ---------------------------------------------------------------------------
// Pass A: level-0 histogram, bins = float-bits >> 23 (clamped to 127).
// ---------------------------------------------------------------------------
__global__ __launch_bounds__(256) void k_histA(
    const float* __restrict__ S, u32* __restrict__ gh) {
  __shared__ u32 h[N_CLS * 129];
  for (int i = threadIdx.x; i < N_CLS * 129; i += 256) h[i] = 0;
  __syncthreads();
  const int per = NELEM / 4 / NBLK;  // 3125
  const float4* S4 = (const float4*)S;
  const int v0 = blockIdx.x * per;
  for (int v = v0 + threadIdx.x; v < v0 + per; v += 256) {
    float4 f = S4[v];
    int c0 = (v * 4) % N_CLS;
    u32 b0 = __float_as_uint(f.x) >> 23; if (b0 > 127u) b0 = 127u;
    u32 b1 = __float_as_uint(f.y) >> 23; if (b1 > 127u) b1 = 127u;
    u32 b2 = __float_as_uint(f.z) >> 23; if (b2 > 127u) b2 = 127u;
    u32 b3 = __float_as_uint(f.w) >> 23; if (b3 > 127u) b3 = 127u;
    atomicAdd(&h[(c0 + 0) * 129 + b0], 1u);
    atomicAdd(&h[(c0 + 1) * 129 + b1], 1u);
    atomicAdd(&h[(c0 + 2) * 129 + b2], 1u);
    atomicAdd(&h[(c0 + 3) * 129 + b3], 1u);
  }
  __syncthreads();
  for (int i = threadIdx.x; i < N_CLS * 128; i += 256) {
    u32 v = h[(i >> 7) * 129 + (i & 127)];
    if (v) atomicAdd(&gh[i], v);
  }
}

// ---------------------------------------------------------------------------
// Pass B fused: each block stages ghistA, derives prefA itself, then builds
// the level-1 histogram over bits [22:15] for elements in the level-0 bin.
// ---------------------------------------------------------------------------
__global__ __launch_bounds__(256) void k_histB_f(
    const float* __restrict__ S, const u32* __restrict__ ghA,
    u32* __restrict__ ghB) {
  __shared__ u32 h[N_CLS * 257];
  __shared__ u32 pA[N_CLS];
  for (int i = threadIdx.x; i < N_CLS * 128; i += 256)
    h[(i >> 7) * 129 + (i & 127)] = ghA[i];
  __syncthreads();
  if (threadIdx.x < N_CLS) {
    const int c = threadIdx.x;
    u32 acc = 0; u32 pref = 0;
    for (int b = 127; b >= 0; --b) {
      acc += h[c * 129 + b];
      if (acc >= TOPK) { pref = (u32)b; break; }
    }
    pA[c] = pref;
  }
  __syncthreads();
  for (int i = threadIdx.x; i < N_CLS * 257; i += 256) h[i] = 0;
  __syncthreads();
  const int per = NELEM / 4 / NBLK;
  const float4* S4 = (const float4*)S;
  const int v0 = blockIdx.x * per;
  for (int v = v0 + threadIdx.x; v < v0 + per; v += 256) {
    float4 f = S4[v];
    int c0 = (v * 4) % N_CLS;
    u32 bb[4] = {__float_as_uint(f.x), __float_as_uint(f.y),
                 __float_as_uint(f.z), __float_as_uint(f.w)};
    #pragma unroll
    for (int k = 0; k < 4; ++k) {
      u32 e = bb[k] >> 23; if (e > 127u) e = 127u;
      if (e == pA[c0 + k])
        atomicAdd(&h[(c0 + k) * 257 + ((bb[k] >> 15) & 0xFF)], 1u);
    }
  }
  __syncthreads();
  for (int i = threadIdx.x; i < N_CLS * 256; i += 256) {
    u32 v = h[(i >> 8) * 257 + (i & 255)];
    if (v) atomicAdd(&ghB[i], v);
  }
}

// ---------------------------------------------------------------------------
// Count fused: stages both hists, derives T16 (target 1000) AND T160
// (target 160; conservative T160=T16 if the 160-crossing leaves the
// level-2 bin range). Block 0 publishes T16/T160/cnt. Then per-block
// per-class counts -> bcnt (plain stores).
// ---------------------------------------------------------------------------
__global__ __launch_bounds__(256) void k_count_f(
    const float* __restrict__ S, const u32* __restrict__ ghA,
    const u32* __restrict__ ghB, u32* __restrict__ T16,
    u32* __restrict__ T160, u32* __restrict__ cnt, u32* __restrict__ bcnt) {
  __shared__ u32 hA[N_CLS * 129];
  __shared__ u32 hB[N_CLS * 257];
  __shared__ u32 tl[N_CLS];
  __shared__ u32 lcnt[N_CLS];
  for (int i = threadIdx.x; i < N_CLS * 128; i += 256)
    hA[(i >> 7) * 129 + (i & 127)] = ghA[i];
  for (int i = threadIdx.x; i < N_CLS * 256; i += 256)
    hB[(i >> 8) * 257 + (i & 255)] = ghB[i];
  for (int i = threadIdx.x; i < N_CLS; i += 256) lcnt[i] = 0;
  __syncthreads();
  if (threadIdx.x < N_CLS) {
    const int c = threadIdx.x;
    u32 acc = 0, pref = 0, tgt = TOPK, aboveA = 0;
    bool found = false;
    for (int b = 127; b >= 0; --b) {
      u32 hv = hA[c * 129 + b];
      acc += hv;
      if (acc >= TOPK) { pref = (u32)b; tgt = TOPK - (acc - hv);
                         aboveA = acc - hv; found = true; break; }
    }
    if (!found) { pref = 0; tgt = TOPK; aboveA = acc - hA[c * 129]; }
    u32 accB = 0, B1 = 0;
    for (int b = 255; b >= 0; --b) {
      accB += hB[c * 257 + b];
      if (accB >= tgt) { B1 = (u32)b; break; }
    }
    u32 t16 = (pref << 23) | (B1 << 15);
    tl[c] = t16;
    if (blockIdx.x == 0) {
      T16[c] = t16;
      cnt[c] = aboveA + accB;
      u32 t160 = t16;  // conservative default
      if (aboveA < 160u) {
        u32 rt = 160u - aboveA;
        u32 acc2 = 0, B2 = 0;
        for (int b = 255; b >= 0; --b) {
          acc2 += hB[c * 257 + b];
          if (acc2 >= rt) { B2 = (u32)b; break; }
        }
        t160 = (pref << 23) | (B2 << 15);
      }
      T160[c] = t160;
    }
  }
  __syncthreads();
  const int per = NELEM / 4 / NBLK;
  const float4* S4 = (const float4*)S;
  const int v0 = blockIdx.x * per;
  for (int v = v0 + threadIdx.x; v < v0 + per; v += 256) {
    float4 f = S4[v];
    const int c0 = (v * 4) % N_CLS;
    u32 bb[4] = {__float_as_uint(f.x), __float_as_uint(f.y),
                 __float_as_uint(f.z), __float_as_uint(f.w)};
    #pragma unroll
    for (int k = 0; k < 4; ++k)
      if (bb[k] >= tl[c0 + k]) atomicAdd(&lcnt[c0 + k], 1u);
  }
  __syncthreads();
  for (int i = threadIdx.x; i < N_CLS; i += 256)
    bcnt[blockIdx.x * N_CLS + i] = lcnt[i];
}

// ---------------------------------------------------------------------------
// Place fused: each block derives gbase[c] = sum of bcnt[b'<b][c], then
// re-reads (L2-hot) and places at reserved offsets.
// ---------------------------------------------------------------------------
__global__ __launch_bounds__(256) void k_place_f(
    const float* __restrict__ S, const u32* __restrict__ T16,
    const u32* __restrict__ bcnt, u64* __restrict__ cand) {
  __shared__ u32 tl[N_CLS];
  __shared__ u32 lcnt[N_CLS];
  __shared__ u32 gbase[N_CLS];
  for (int i = threadIdx.x; i < N_CLS; i += 256) { tl[i] = T16[i]; lcnt[i] = 0; }
  if (threadIdx.x < N_CLS) {
    const int c = threadIdx.x;
    u32 a = 0;
    for (int b = 0; b < blockIdx.x; ++b) a += bcnt[b * N_CLS + c];
    gbase[c] = a;
  }
  __syncthreads();
  const int per = NELEM / 4 / NBLK;
  const float4* S4 = (const float4*)S;
  const int v0 = blockIdx.x * per;
  for (int v = v0 + threadIdx.x; v < v0 + per; v += 256) {
    float4 f = S4[v];
    const int base = v * 4;
    const int c0 = base % N_CLS;
    const u32 row = (u32)(base / N_CLS);
    u32 bb[4] = {__float_as_uint(f.x), __float_as_uint(f.y),
                 __float_as_uint(f.z), __float_as_uint(f.w)};
    #pragma unroll
    for (int k = 0; k < 4; ++k) {
      if (bb[k] >= tl[c0 + k]) {
        u32 p = gbase[c0 + k] + atomicAdd(&lcnt[c0 + k], 1u);
        if (p < CANDS)
          cand[(size_t)(c0 + k) * CANDS + p] = ((u64)bb[k] << 32) | (u32)(~row);
      }
    }
  }
}

// ---------------------------------------------------------------------------
// Sort+NMS, SINGLE WAVE (64 thr), ZERO __syncthreads on the fast path.
// R24 found ~12 block barriers ~ 14 us were the largest share; all phases
// here are <=256 elements so one wave loses little width (R14's trap was
// 8000-element phases). Filter via ballot-prefix (no LDS atomics), 256-key
// bitonic fully wave-lockstep (identical network, global-index direction),
// 4-round stage, serial greedy (was single-wave already), tail zero-fill.
// Trusted iff count==100 or a REAL row broke <=CONF; else same wave runs
// the exact full 2048-key path (adversarial only, never on this data).
// ---------------------------------------------------------------------------
__global__ __launch_bounds__(64) void k_sortnms(
    const u64* __restrict__ cand, const u32* __restrict__ cnt,
    const u32* __restrict__ T160, const float* __restrict__ boxes,
    float* __restrict__ cls_out) {
  const int c = blockIdx.x;
  const int lane = threadIdx.x;
  __shared__ u64 keys[SORTN];     // 16384 B (fast path uses first 256)
  __shared__ float4 sbox[TOPK];   // 16000 B
  __shared__ float sarea[TOPK];
  __shared__ float sscore[TOPK];

  u32 n = cnt[c]; if (n > CANDS) n = CANDS;
  const u32 thr = T160[c];
  #pragma unroll
  for (int q = 0; q < FASTN / 64; ++q) keys[lane + q * 64] = 0ull;
  __builtin_amdgcn_wave_barrier();

  // ballot-prefix filter: keys >= T160, order-compacted (order irrelevant:
  // full-key sort downstream). nk > FASTN -> overflow -> full path.
  u32 base = 0;
  for (int i0 = 0; i0 < (int)n; i0 += 64) {
    int i = i0 + lane;
    u64 kk = (i < (int)n) ? cand[(size_t)c * CANDS + i] : 0ull;
    bool take = (i < (int)n) && ((u32)(kk >> 32) >= thr);
    u64 m = __ballot(take);
    if (take) {
      u32 pos = base + (u32)__popcll(m & ((1ull << lane) - 1ull));
      if (pos < FASTN) keys[pos] = kk;
    }
    base += (u32)__popcll(m);
  }
  __builtin_amdgcn_wave_barrier();
  const u32 nk = base;
  bool fastok = (nk <= FASTN);

  if (fastok) {
    // bitonic sort 256 desc, fully wave-lockstep (2 disjoint pairs/lane)
    for (int k = 2; k <= FASTN; k <<= 1) {
      for (int j = k >> 1; j > 0; j >>= 1) {
        #pragma unroll
        for (int q = 0; q < 2; ++q) {
          int p = lane + q * 64;  // 128 pairs
          int i  = ((p & ~(j - 1)) << 1) | (p & (j - 1));
          int ix = i | j;
          bool up = (i & k) == 0;
          u64 a = keys[i], b = keys[ix];
          if (up ? (a < b) : (a > b)) { keys[i] = b; keys[ix] = a; }
        }
        __builtin_amdgcn_wave_barrier();
      }
    }

    // stage 256 boxes/areas/scores from sorted keys (4 rounds)
    #pragma unroll
    for (int q = 0; q < FASTN / 64; ++q) {
      int i = lane + q * 64;
      u64 kk = keys[i];
      u32 idx = ~(u32)kk;
      if (kk == 0ull || idx >= N_DET) idx = 0;
      float4 b = ((const float4*)boxes)[idx];
      sbox[i] = b;
      sarea[i] = (b.z - b.x) * (b.w - b.y);
      sscore[i] = __uint_as_float((u32)(kk >> 32));
    }
    __builtin_amdgcn_wave_barrier();

    // serial greedy, kept boxes in lane registers (2/lane)
    float4 kb0 = make_float4(0.f, 0.f, 0.f, 0.f), kb1 = kb0;
    float ka0 = 0.f, ka1 = 0.f;
    int count = 0;
    bool confbreak = false;
    int ii = 0;
    float sc_n = sscore[0];
    float4 b_n = sbox[0];
    float a_n = sarea[0];
    for (; ii < FASTN && count < 100; ++ii) {
      float sc = sc_n;
      float4 bi = b_n;
      float ai = a_n;
      if (ii + 1 < FASTN) {
        sc_n = sscore[ii + 1];
        b_n = sbox[ii + 1];
        a_n = sarea[ii + 1];
      }
      if (!(sc > CONF)) { confbreak = true; break; }
      bool sup0 = (lane < count) && iou_gt_half(kb0, ka0, bi, ai);
      bool sup1 = (lane + 64 < count) && iou_gt_half(kb1, ka1, bi, ai);
      u64 m = __ballot(sup0 || sup1);
      if (m == 0ull) {
        if (count < 64) {
          if (lane == count) { kb0 = bi; ka0 = ai; }
        } else {
          if (lane == count - 64) { kb1 = bi; ka1 = ai; }
        }
        if (lane == 0) cls_out[c * 128 + count] = sc;
        ++count;
      }
    }
    bool done = (count >= 100) || (confbreak && ii < (int)nk);
    if (done) {
      for (int i = count + lane; i < 100; i += 64)
        cls_out[c * 128 + i] = 0.0f;
      return;  // wave-uniform
    }
  }

  // ---- full path (adversarial only): sort all 2048 single-wave ----
  for (int i = lane; i < SORTN; i += 64)
    keys[i] = (i < (int)n) ? cand[(size_t)c * CANDS + i] : 0ull;
  __builtin_amdgcn_wave_barrier();
  for (int k = 2; k <= SORTN; k <<= 1) {
    for (int j = k >> 1; j > 0; j >>= 1) {
      for (int p = lane; p < SORTN / 2; p += 64) {
        int i  = ((p & ~(j - 1)) << 1) | (p & (j - 1));
        int ix = i | j;
        bool up = (i & k) == 0;
        u64 a = keys[i], b = keys[ix];
        if (up ? (a < b) : (a > b)) { keys[i] = b; keys[ix] = a; }
      }
      __builtin_amdgcn_wave_barrier();
    }
  }
  for (int i = lane; i < TOPK; i += 64) {
    u64 kk = keys[i];
    u32 idx = ~(u32)kk;
    if (kk == 0ull || idx >= N_DET) idx = 0;
    float4 b = ((const float4*)boxes)[idx];
    sbox[i] = b;
    sarea[i] = (b.z - b.x) * (b.w - b.y);
    sscore[i] = __uint_as_float((u32)(kk >> 32));
  }
  __builtin_amdgcn_wave_barrier();
  {
    float4 kb0 = make_float4(0.f, 0.f, 0.f, 0.f), kb1 = kb0;
    float ka0 = 0.f, ka1 = 0.f;
    int count = 0;
    float sc_n = sscore[0];
    float4 b_n = sbox[0];
    float a_n = sarea[0];
    for (int i = 0; i < TOPK && count < 100; ++i) {
      float sc = sc_n;
      float4 bi = b_n;
      float ai = a_n;
      if (i + 1 < TOPK) {
        sc_n = sscore[i + 1];
        b_n = sbox[i + 1];
        a_n = sarea[i + 1];
      }
      if (!(sc > CONF)) break;
      bool sup0 = (lane < count) && iou_gt_half(kb0, ka0, bi, ai);
      bool sup1 = (lane + 64 < count) && iou_gt_half(kb1, ka1, bi, ai);
      u64 m = __ballot(sup0 || sup1);
      if (m == 0ull) {
        if (count < 64) {
          if (lane == count) { kb0 = bi; ka0 = ai; }
        } else {
          if (lane == count - 64) { kb1 = bi; ka1 = ai; }
        }
        if (lane == 0) cls_out[c * 128 + count] = sc;
        ++count;
      }
    }
    for (int i = count + lane; i < 100; i += 64)
      cls_out[c * 128 + i] = 0.0f;
  }
}

// ---------------------------------------------------------------------------
// Global top-100: hybrid two-level radix select, 1024 thr, 8 syncthreads.
// Fallback (nc>512, adversarial ties): multi-wave 8192 sort.
// ---------------------------------------------------------------------------
__global__ __launch_bounds__(1024) void k_final(
    const float* __restrict__ cls_out, float* __restrict__ out) {
  __shared__ u32 vals[8000];
  __shared__ u32 h1[8192];
  __shared__ u32 h2[16384];
  __shared__ u32 wsum[16];
  __shared__ u32 cands[512];
  __shared__ u32 sPref, sT2, sThr, scnt;
  const int t = threadIdx.x, wave = t >> 6, lane = t & 63;

  uint4 z4 = make_uint4(0u, 0u, 0u, 0u);
  for (int i = t; i < 2048; i += 1024) ((uint4*)h1)[i] = z4;
  for (int i = t; i < 4096; i += 1024) ((uint4*)h2)[i] = z4;
  if (t < 128) ((uint4*)cands)[t] = z4;
  if (t == 0) { sPref = 0; sT2 = 1; sThr = 0; scnt = 0; }
  __syncthreads();  // B1

  for (int i = t; i < 8000; i += 1024) {
    u32 b = __float_as_uint(cls_out[(i / 100) * 128 + (i % 100)]);
    vals[i] = b;
    u32 bin = b >> 17; if (bin > 8191u) bin = 8191u;
    atomicAdd(&h1[bin], 1u);
  }
  __syncthreads();  // B2

  {
    const u32 b0 = (u32)t * 8u;
    u32 loc[8]; u32 lsum = 0;
    #pragma unroll
    for (int k = 0; k < 8; ++k) { loc[k] = h1[b0 + k]; lsum += loc[k]; }
    u32 s = lsum;
    #pragma unroll
    for (int off = 1; off < 64; off <<= 1) {
      u32 v = __shfl_down(s, off, 64);
      if (lane + off < 64) s += v;
    }
    if (lane == 0) wsum[wave] = s;
    __syncthreads();  // B3
    u32 aboveW = 0;
    #pragma unroll
    for (int w = 0; w < 16; ++w) if (w > wave) aboveW += wsum[w];
    u32 above = aboveW + (s - lsum);
    if (above < 100u && above + lsum >= 100u) {
      u32 acc = above;
      #pragma unroll
      for (int k = 7; k >= 0; --k) {
        acc += loc[k];
        if (acc >= 100u) { sPref = b0 + (u32)k; sT2 = 100u - (acc - loc[k]); break; }
      }
    }
    __syncthreads();  // B4
  }
  const u32 pref = sPref, rt = sT2;

  for (int i = t; i < 8000; i += 1024) {
    u32 b = vals[i];
    u32 bin = b >> 17; if (bin > 8191u) bin = 8191u;
    if (bin == pref) atomicAdd(&h2[(b >> 3) & 0x3FFFu], 1u);
  }
  __syncthreads();  // B5

  {
    const u32 b0 = (u32)t * 16u;
    u32 loc[16]; u32 lsum = 0;
    #pragma unroll
    for (int k = 0; k < 16; ++k) { loc[k] = h2[b0 + k]; lsum += loc[k]; }
    u32 s = lsum;
    #pragma unroll
    for (int off = 1; off < 64; off <<= 1) {
      u32 v = __shfl_down(s, off, 64);
      if (lane + off < 64) s += v;
    }
    if (lane == 0) wsum[wave] = s;
    __syncthreads();  // B6
    u32 aboveW = 0;
    #pragma unroll
    for (int w = 0; w < 16; ++w) if (w > wave) aboveW += wsum[w];
    u32 above = aboveW + (s - lsum);
    if (above < rt && above + lsum >= rt) {
      u32 acc = above;
      #pragma unroll
      for (int k = 15; k >= 0; --k) {
        acc += loc[k];
        if (acc >= rt) { sThr = (pref << 17) | ((b0 + (u32)k) << 3); break; }
      }
    }
    __syncthreads();  // B7
  }
  const u32 thr = sThr;

  for (int i = t; i < 8000; i += 1024) {
    u32 v = vals[i];
    if (v >= thr) {
      u32 p = atomicAdd(&scnt, 1u);
      if (p < 512u) cands[p] = v;
    }
  }
  __syncthreads();  // B8
  const u32 nc = scnt;

  if (nc <= 512u) {
    if (wave == 0) {
      for (int k = 2; k <= 512; k <<= 1)
        for (int j = k >> 1; j > 0; j >>= 1) {
          for (int p = lane; p < 256; p += 64) {
            int i  = ((p & ~(j - 1)) << 1) | (p & (j - 1));
            int ix = i | j;
            bool up = (i & k) == 0;
            u32 a = cands[i], b = cands[ix];
            if (up ? (a < b) : (a > b)) { cands[i] = b; cands[ix] = a; }
          }
          __builtin_amdgcn_wave_barrier();
        }
      out[lane] = __uint_as_float(cands[lane]);
      if (lane < 36) out[lane + 64] = __uint_as_float(cands[lane + 64]);
    }
  } else {
    for (int i = t; i < 8192; i += 1024) h2[i] = (i < 8000) ? vals[i] : 0u;
    __syncthreads();
    for (int k = 2; k <= 8192; k <<= 1)
      for (int j = k >> 1; j > 0; j >>= 1) {
        for (int p = t; p < 4096; p += 1024) {
          int i  = ((p & ~(j - 1)) << 1) | (p & (j - 1));
          int ix = i | j;
          bool up = (i & k) == 0;
          u32 a = h2[i], b = h2[ix];
          if (up ? (a < b) : (a > b)) { h2[i] = b; h2[ix] = a; }
        }
        __syncthreads();
      }
    if (t < 100) out[t] = __uint_as_float(h2[t]);
  }
}

extern "C" void kernel_launch(void* const* d_in, const int* in_sizes, int n_in,
                              void* d_out, int out_size, void* d_ws, size_t ws_size,
                              hipStream_t stream) {
  const float* scores = (const float*)d_in[0];
  const float* boxes  = (const float*)d_in[1];
  float* out = (float*)d_out;
  char* ws = (char*)d_ws;

  u32* T16     = (u32*)(ws + OFF_T16);
  u32* T160    = (u32*)(ws + OFF_T160);
  u32* cnt     = (u32*)(ws + OFF_CNT);
  float* cls_out = (float*)(ws + OFF_CLSOUT);
  u32* ghistA  = (u32*)(ws + OFF_GHA);
  u32* ghistB  = (u32*)(ws + OFF_GHB);
  u64* cand    = (u64*)(ws + OFF_CAND);
  u32* bcnt    = (u32*)(ws + OFF_BCNT);

  k_zero<<<30, 256, 0, stream>>>(ghistA);  // zeros ghistA+ghistB (contiguous)
  k_histA<<<NBLK, 256, 0, stream>>>(scores, ghistA);
  k_histB_f<<<NBLK, 256, 0, stream>>>(scores, ghistA, ghistB);
  k_count_f<<<NBLK, 256, 0, stream>>>(scores, ghistA, ghistB, T16, T160, cnt, bcnt);
  k_place_f<<<NBLK, 256, 0, stream>>>(scores, T16, bcnt, cand);
  k_sortnms<<<N_CLS, 64, 0, stream>>>(cand, cnt, T160, boxes, cls_out);
  k_final<<<1, 1024, 0, stream>>>(cls_out, out);
}

// Round 26
// 143.768 us; speedup vs baseline: 1.0712x; 1.0712x over previous
//
#include <hip/hip_runtime.h>
#include <stdint.h>

#define N_DET 20000
#define N_CLS 80
#define NELEM (N_DET * N_CLS)
#define TOPK  1000
#define CONF  0.05f
#define CANDS 1280
#define SORTN 2048
#define FASTN 256
#define NBLK  128  // blocks for hist/count/place passes (3125 float4 each)

typedef unsigned long long u64;
typedef unsigned int u32;

// Exact replication of RN(inter/denom) > 0.5 without fdiv:
// RN(a/b) > 0.5  <=>  a/b > 0.5 + 2^-25 (tie rounds-to-even to 0.5)
//               <=>  a * 2^25 > b * (2^24 + 1), both products exact in f64.
__device__ __forceinline__ bool iou_gt_half(float4 bi, float ai,
                                            float4 bj, float aj) {
  #pragma clang fp contract(off)
  float iw = fmaxf(fminf(bi.z, bj.z) - fmaxf(bi.x, bj.x), 0.0f);
  float ih = fmaxf(fminf(bi.w, bj.w) - fmaxf(bi.y, bj.y), 0.0f);
  float inter = iw * ih;
  float denom = ai + aj - inter + 1e-9f;
  return (double)inter * 33554432.0 > (double)denom * 16777217.0;
}

// ---------------------------------------------------------------------------
// Workspace layout (total 1,706,240 B - NO overlaps):
//   T16 @0 (320) | T160 @320 (320) | cnt @960 (320)
//   cls_out @641280 (40960)   [fully written each call]
//   ghistA @682240 (40960) | ghistB @723200 (81920)   [zeroed by k_zero]
//   cand @805120 (819200) | bcnt @1624320 (40960)
// ---------------------------------------------------------------------------
#define OFF_T16    0
#define OFF_T160   320
#define OFF_CNT    960
#define OFF_CLSOUT 641280
#define OFF_GHA    682240
#define OFF_GHB    723200
#define OFF_CAND   805120
#define OFF_BCNT   1624320

// Zero ghistA+ghistB (contiguous 122880 B = 7680 uint4).
__global__ __launch_bounds__(256) void k_zero(u32* __restrict__ gh) {
  uint4 z4 = make_uint4(0u, 0u, 0u, 0u);
  uint4* p = (uint4*)gh;
  int i = blockIdx.x * 256 + threadIdx.x;
  if (i < 7680) p[i] = z4;
}

// ---------------------------------------------------------------------------
// Pass A: level-0 histogram, bins = float-bits >> 23 (clamped to 127).
// ---------------------------------------------------------------------------
__global__ __launch_bounds__(256) void k_histA(
    const float* __restrict__ S, u32* __restrict__ gh) {
  __shared__ u32 h[N_CLS * 129];
  for (int i = threadIdx.x; i < N_CLS * 129; i += 256) h[i] = 0;
  __syncthreads();
  const int per = NELEM / 4 / NBLK;  // 3125
  const float4* S4 = (const float4*)S;
  const int v0 = blockIdx.x * per;
  for (int v = v0 + threadIdx.x; v < v0 + per; v += 256) {
    float4 f = S4[v];
    int c0 = (v * 4) % N_CLS;
    u32 b0 = __float_as_uint(f.x) >> 23; if (b0 > 127u) b0 = 127u;
    u32 b1 = __float_as_uint(f.y) >> 23; if (b1 > 127u) b1 = 127u;
    u32 b2 = __float_as_uint(f.z) >> 23; if (b2 > 127u) b2 = 127u;
    u32 b3 = __float_as_uint(f.w) >> 23; if (b3 > 127u) b3 = 127u;
    atomicAdd(&h[(c0 + 0) * 129 + b0], 1u);
    atomicAdd(&h[(c0 + 1) * 129 + b1], 1u);
    atomicAdd(&h[(c0 + 2) * 129 + b2], 1u);
    atomicAdd(&h[(c0 + 3) * 129 + b3], 1u);
  }
  __syncthreads();
  for (int i = threadIdx.x; i < N_CLS * 128; i += 256) {
    u32 v = h[(i >> 7) * 129 + (i & 127)];
    if (v) atomicAdd(&gh[i], v);
  }
}

// ---------------------------------------------------------------------------
// Pass B fused: each block stages ghistA, derives prefA itself, then builds
// the level-1 histogram over bits [22:15] for elements in the level-0 bin.
// ---------------------------------------------------------------------------
__global__ __launch_bounds__(256) void k_histB_f(
    const float* __restrict__ S, const u32* __restrict__ ghA,
    u32* __restrict__ ghB) {
  __shared__ u32 h[N_CLS * 257];
  __shared__ u32 pA[N_CLS];
  for (int i = threadIdx.x; i < N_CLS * 128; i += 256)
    h[(i >> 7) * 129 + (i & 127)] = ghA[i];
  __syncthreads();
  if (threadIdx.x < N_CLS) {
    const int c = threadIdx.x;
    u32 acc = 0; u32 pref = 0;
    for (int b = 127; b >= 0; --b) {
      acc += h[c * 129 + b];
      if (acc >= TOPK) { pref = (u32)b; break; }
    }
    pA[c] = pref;
  }
  __syncthreads();
  for (int i = threadIdx.x; i < N_CLS * 257; i += 256) h[i] = 0;
  __syncthreads();
  const int per = NELEM / 4 / NBLK;
  const float4* S4 = (const float4*)S;
  const int v0 = blockIdx.x * per;
  for (int v = v0 + threadIdx.x; v < v0 + per; v += 256) {
    float4 f = S4[v];
    int c0 = (v * 4) % N_CLS;
    u32 bb[4] = {__float_as_uint(f.x), __float_as_uint(f.y),
                 __float_as_uint(f.z), __float_as_uint(f.w)};
    #pragma unroll
    for (int k = 0; k < 4; ++k) {
      u32 e = bb[k] >> 23; if (e > 127u) e = 127u;
      if (e == pA[c0 + k])
        atomicAdd(&h[(c0 + k) * 257 + ((bb[k] >> 15) & 0xFF)], 1u);
    }
  }
  __syncthreads();
  for (int i = threadIdx.x; i < N_CLS * 256; i += 256) {
    u32 v = h[(i >> 8) * 257 + (i & 255)];
    if (v) atomicAdd(&ghB[i], v);
  }
}

// ---------------------------------------------------------------------------
// Count fused: stages both hists, derives T16 (target 1000) AND T160
// (target 160; conservative T160=T16 if the 160-crossing leaves the
// level-2 bin range). Block 0 publishes T16/T160/cnt. Then per-block
// per-class counts -> bcnt (plain stores).
// ---------------------------------------------------------------------------
__global__ __launch_bounds__(256) void k_count_f(
    const float* __restrict__ S, const u32* __restrict__ ghA,
    const u32* __restrict__ ghB, u32* __restrict__ T16,
    u32* __restrict__ T160, u32* __restrict__ cnt, u32* __restrict__ bcnt) {
  __shared__ u32 hA[N_CLS * 129];
  __shared__ u32 hB[N_CLS * 257];
  __shared__ u32 tl[N_CLS];
  __shared__ u32 lcnt[N_CLS];
  for (int i = threadIdx.x; i < N_CLS * 128; i += 256)
    hA[(i >> 7) * 129 + (i & 127)] = ghA[i];
  for (int i = threadIdx.x; i < N_CLS * 256; i += 256)
    hB[(i >> 8) * 257 + (i & 255)] = ghB[i];
  for (int i = threadIdx.x; i < N_CLS; i += 256) lcnt[i] = 0;
  __syncthreads();
  if (threadIdx.x < N_CLS) {
    const int c = threadIdx.x;
    u32 acc = 0, pref = 0, tgt = TOPK, aboveA = 0;
    bool found = false;
    for (int b = 127; b >= 0; --b) {
      u32 hv = hA[c * 129 + b];
      acc += hv;
      if (acc >= TOPK) { pref = (u32)b; tgt = TOPK - (acc - hv);
                         aboveA = acc - hv; found = true; break; }
    }
    if (!found) { pref = 0; tgt = TOPK; aboveA = acc - hA[c * 129]; }
    u32 accB = 0, B1 = 0;
    for (int b = 255; b >= 0; --b) {
      accB += hB[c * 257 + b];
      if (accB >= tgt) { B1 = (u32)b; break; }
    }
    u32 t16 = (pref << 23) | (B1 << 15);
    tl[c] = t16;
    if (blockIdx.x == 0) {
      T16[c] = t16;
      cnt[c] = aboveA + accB;
      u32 t160 = t16;  // conservative default
      if (aboveA < 160u) {
        u32 rt = 160u - aboveA;
        u32 acc2 = 0, B2 = 0;
        for (int b = 255; b >= 0; --b) {
          acc2 += hB[c * 257 + b];
          if (acc2 >= rt) { B2 = (u32)b; break; }
        }
        t160 = (pref << 23) | (B2 << 15);
      }
      T160[c] = t160;
    }
  }
  __syncthreads();
  const int per = NELEM / 4 / NBLK;
  const float4* S4 = (const float4*)S;
  const int v0 = blockIdx.x * per;
  for (int v = v0 + threadIdx.x; v < v0 + per; v += 256) {
    float4 f = S4[v];
    const int c0 = (v * 4) % N_CLS;
    u32 bb[4] = {__float_as_uint(f.x), __float_as_uint(f.y),
                 __float_as_uint(f.z), __float_as_uint(f.w)};
    #pragma unroll
    for (int k = 0; k < 4; ++k)
      if (bb[k] >= tl[c0 + k]) atomicAdd(&lcnt[c0 + k], 1u);
  }
  __syncthreads();
  for (int i = threadIdx.x; i < N_CLS; i += 256)
    bcnt[blockIdx.x * N_CLS + i] = lcnt[i];
}

// ---------------------------------------------------------------------------
// Place fused: each block derives gbase[c] = sum of bcnt[b'<b][c], then
// re-reads (L2-hot) and places at reserved offsets.
// ---------------------------------------------------------------------------
__global__ __launch_bounds__(256) void k_place_f(
    const float* __restrict__ S, const u32* __restrict__ T16,
    const u32* __restrict__ bcnt, u64* __restrict__ cand) {
  __shared__ u32 tl[N_CLS];
  __shared__ u32 lcnt[N_CLS];
  __shared__ u32 gbase[N_CLS];
  for (int i = threadIdx.x; i < N_CLS; i += 256) { tl[i] = T16[i]; lcnt[i] = 0; }
  if (threadIdx.x < N_CLS) {
    const int c = threadIdx.x;
    u32 a = 0;
    for (int b = 0; b < blockIdx.x; ++b) a += bcnt[b * N_CLS + c];
    gbase[c] = a;
  }
  __syncthreads();
  const int per = NELEM / 4 / NBLK;
  const float4* S4 = (const float4*)S;
  const int v0 = blockIdx.x * per;
  for (int v = v0 + threadIdx.x; v < v0 + per; v += 256) {
    float4 f = S4[v];
    const int base = v * 4;
    const int c0 = base % N_CLS;
    const u32 row = (u32)(base / N_CLS);
    u32 bb[4] = {__float_as_uint(f.x), __float_as_uint(f.y),
                 __float_as_uint(f.z), __float_as_uint(f.w)};
    #pragma unroll
    for (int k = 0; k < 4; ++k) {
      if (bb[k] >= tl[c0 + k]) {
        u32 p = gbase[c0 + k] + atomicAdd(&lcnt[c0 + k], 1u);
        if (p < CANDS)
          cand[(size_t)(c0 + k) * CANDS + p] = ((u64)bb[k] << 32) | (u32)(~row);
      }
    }
  }
}

// ---------------------------------------------------------------------------
// Sort+NMS, 256 thr. FAST: filter to keys >= T160 (prefix of the full
// order), sort 256 keys (4 waves x 64-seg, 6 block barriers), greedy.
// Trusted iff count==100 or a REAL row broke <=CONF; else the SAME block
// re-runs the exact full 2048-key path inline (no extra dispatch).
// ---------------------------------------------------------------------------
__global__ __launch_bounds__(256) void k_sortnms(
    const u64* __restrict__ cand, const u32* __restrict__ cnt,
    const u32* __restrict__ T160, const float* __restrict__ boxes,
    float* __restrict__ cls_out) {
  const int c = blockIdx.x;
  const int tid = threadIdx.x, wave = tid >> 6, lane = tid & 63;
  __shared__ u64 keys[SORTN];     // 16384 B (fast path uses first 256)
  __shared__ float4 sbox[TOPK];   // 16000 B
  __shared__ float sarea[TOPK];
  __shared__ float sscore[TOPK];
  __shared__ u32 sN, sOvf, sDone;

  u32 n = cnt[c]; if (n > CANDS) n = CANDS;
  const u32 thr = T160[c];
  keys[tid] = 0ull;
  if (tid == 0) { sN = 0; sOvf = 0; sDone = 0; }
  __syncthreads();
  for (int i = tid; i < (int)n; i += 256) {
    u64 kk = cand[(size_t)c * CANDS + i];
    if ((u32)(kk >> 32) >= thr) {
      u32 p = atomicAdd(&sN, 1u);
      if (p < FASTN) keys[p] = kk; else sOvf = 1u;
    }
  }
  __syncthreads();
  const u32 nk = sN;

  if (!sOvf) {
    // bitonic sort 256 (desc); 4 waves x 64-key segments
    const int segbase = wave * 64;
    for (int k = 2; k <= 64; k <<= 1) {
      for (int j = k >> 1; j > 0; j >>= 1) {
        if (lane < 32) {
          int p = lane;
          int i  = segbase + (((p & ~(j - 1)) << 1) | (p & (j - 1)));
          int ix = i | j;
          bool up = (i & k) == 0;
          u64 a = keys[i], b = keys[ix];
          if (up ? (a < b) : (a > b)) { keys[i] = b; keys[ix] = a; }
        }
        __builtin_amdgcn_wave_barrier();
      }
    }
    __syncthreads();
    for (int k = 128; k <= FASTN; k <<= 1) {
      for (int j = k >> 1; j >= 64; j >>= 1) {
        if (tid < 128) {
          int p = tid;
          int i  = ((p & ~(j - 1)) << 1) | (p & (j - 1));
          int ix = i | j;
          bool up = (i & k) == 0;
          u64 a = keys[i], b = keys[ix];
          if (up ? (a < b) : (a > b)) { keys[i] = b; keys[ix] = a; }
        }
        __syncthreads();
      }
      for (int j = 32; j > 0; j >>= 1) {
        if (lane < 32) {
          int p = lane;
          int i  = segbase + (((p & ~(j - 1)) << 1) | (p & (j - 1)));
          int ix = i | j;
          bool up = (i & k) == 0;
          u64 a = keys[i], b = keys[ix];
          if (up ? (a < b) : (a > b)) { keys[i] = b; keys[ix] = a; }
        }
        __builtin_amdgcn_wave_barrier();
      }
      __syncthreads();
    }

    // stage 256 boxes/areas/scores from sorted keys
    {
      u64 kk = keys[tid];
      u32 idx = ~(u32)kk;
      if (kk == 0ull || idx >= N_DET) idx = 0;
      float4 b = ((const float4*)boxes)[idx];
      sbox[tid] = b;
      sarea[tid] = (b.z - b.x) * (b.w - b.y);
      sscore[tid] = __uint_as_float((u32)(kk >> 32));
    }
    __syncthreads();

    if (wave == 0) {
      float4 kb0 = make_float4(0.f, 0.f, 0.f, 0.f), kb1 = kb0;
      float ka0 = 0.f, ka1 = 0.f;
      int count = 0;
      bool confbreak = false;
      int ii = 0;
      float sc_n = sscore[0];
      float4 b_n = sbox[0];
      float a_n = sarea[0];
      for (; ii < FASTN && count < 100; ++ii) {
        float sc = sc_n;
        float4 bi = b_n;
        float ai = a_n;
        if (ii + 1 < FASTN) {
          sc_n = sscore[ii + 1];
          b_n = sbox[ii + 1];
          a_n = sarea[ii + 1];
        }
        if (!(sc > CONF)) { confbreak = true; break; }
        bool sup0 = (lane < count) && iou_gt_half(kb0, ka0, bi, ai);
        bool sup1 = (lane + 64 < count) && iou_gt_half(kb1, ka1, bi, ai);
        u64 m = __ballot(sup0 || sup1);
        if (m == 0ull) {
          if (count < 64) {
            if (lane == count) { kb0 = bi; ka0 = ai; }
          } else {
            if (lane == count - 64) { kb1 = bi; ka1 = ai; }
          }
          if (lane == 0) cls_out[c * 128 + count] = sc;
          ++count;
        }
      }
      bool done = (count >= 100) || (confbreak && ii < (int)nk);
      if (lane == 0) sDone = done ? 1u : 0u;
      if (done) {
        for (int i = count + lane; i < 100; i += 64)
          cls_out[c * 128 + i] = 0.0f;
      }
    }
  }
  __syncthreads();
  if (sDone) return;

  // ---- full path (adversarial only): sort all 2048, full greedy ----
  for (int i = tid; i < SORTN; i += 256)
    keys[i] = (i < (int)n) ? cand[(size_t)c * CANDS + i] : 0ull;
  __syncthreads();
  const int seg2 = wave * 512;  // 4 waves x 512-key segments
  for (int k = 2; k <= 512; k <<= 1) {
    for (int j = k >> 1; j > 0; j >>= 1) {
      #pragma unroll
      for (int q = 0; q < 4; ++q) {
        int p = lane + q * 64;  // 256 pairs per segment stage
        int i  = seg2 + (((p & ~(j - 1)) << 1) | (p & (j - 1)));
        int ix = i | j;
        bool up = (i & k) == 0;
        u64 a = keys[i], b = keys[ix];
        if (up ? (a < b) : (a > b)) { keys[i] = b; keys[ix] = a; }
      }
      __builtin_amdgcn_wave_barrier();
    }
  }
  __syncthreads();
  for (int k = 1024; k <= SORTN; k <<= 1) {
    for (int j = k >> 1; j >= 512; j >>= 1) {
      for (int p = tid; p < SORTN / 2; p += 256) {
        int i  = ((p & ~(j - 1)) << 1) | (p & (j - 1));
        int ix = i | j;
        bool up = (i & k) == 0;
        u64 a = keys[i], b = keys[ix];
        if (up ? (a < b) : (a > b)) { keys[i] = b; keys[ix] = a; }
      }
      __syncthreads();
    }
    for (int j = 256; j > 0; j >>= 1) {
      #pragma unroll
      for (int q = 0; q < 4; ++q) {
        int p = lane + q * 64;
        int i  = seg2 + (((p & ~(j - 1)) << 1) | (p & (j - 1)));
        int ix = i | j;
        bool up = (i & k) == 0;
        u64 a = keys[i], b = keys[ix];
        if (up ? (a < b) : (a > b)) { keys[i] = b; keys[ix] = a; }
      }
      __builtin_amdgcn_wave_barrier();
    }
    __syncthreads();
  }
  for (int i = tid; i < TOPK; i += 256) {
    u64 kk = keys[i];
    u32 idx = ~(u32)kk;
    if (kk == 0ull || idx >= N_DET) idx = 0;
    float4 b = ((const float4*)boxes)[idx];
    sbox[i] = b;
    sarea[i] = (b.z - b.x) * (b.w - b.y);
    sscore[i] = __uint_as_float((u32)(kk >> 32));
  }
  __syncthreads();
  if (wave == 0) {
    float4 kb0 = make_float4(0.f, 0.f, 0.f, 0.f), kb1 = kb0;
    float ka0 = 0.f, ka1 = 0.f;
    int count = 0;
    float sc_n = sscore[0];
    float4 b_n = sbox[0];
    float a_n = sarea[0];
    for (int i = 0; i < TOPK && count < 100; ++i) {
      float sc = sc_n;
      float4 bi = b_n;
      float ai = a_n;
      if (i + 1 < TOPK) {
        sc_n = sscore[i + 1];
        b_n = sbox[i + 1];
        a_n = sarea[i + 1];
      }
      if (!(sc > CONF)) break;
      bool sup0 = (lane < count) && iou_gt_half(kb0, ka0, bi, ai);
      bool sup1 = (lane + 64 < count) && iou_gt_half(kb1, ka1, bi, ai);
      u64 m = __ballot(sup0 || sup1);
      if (m == 0ull) {
        if (count < 64) {
          if (lane == count) { kb0 = bi; ka0 = ai; }
        } else {
          if (lane == count - 64) { kb1 = bi; ka1 = ai; }
        }
        if (lane == 0) cls_out[c * 128 + count] = sc;
        ++count;
      }
    }
    for (int i = count + lane; i < 100; i += 64)
      cls_out[c * 128 + i] = 0.0f;
  }
}

// ---------------------------------------------------------------------------
// Global top-100: hybrid two-level radix select, 1024 thr, 8 syncthreads.
// Fallback (nc>512, adversarial ties): multi-wave 8192 sort.
// ---------------------------------------------------------------------------
__global__ __launch_bounds__(1024) void k_final(
    const float* __restrict__ cls_out, float* __restrict__ out) {
  __shared__ u32 vals[8000];
  __shared__ u32 h1[8192];
  __shared__ u32 h2[16384];
  __shared__ u32 wsum[16];
  __shared__ u32 cands[512];
  __shared__ u32 sPref, sT2, sThr, scnt;
  const int t = threadIdx.x, wave = t >> 6, lane = t & 63;

  uint4 z4 = make_uint4(0u, 0u, 0u, 0u);
  for (int i = t; i < 2048; i += 1024) ((uint4*)h1)[i] = z4;
  for (int i = t; i < 4096; i += 1024) ((uint4*)h2)[i] = z4;
  if (t < 128) ((uint4*)cands)[t] = z4;
  if (t == 0) { sPref = 0; sT2 = 1; sThr = 0; scnt = 0; }
  __syncthreads();  // B1

  for (int i = t; i < 8000; i += 1024) {
    u32 b = __float_as_uint(cls_out[(i / 100) * 128 + (i % 100)]);
    vals[i] = b;
    u32 bin = b >> 17; if (bin > 8191u) bin = 8191u;
    atomicAdd(&h1[bin], 1u);
  }
  __syncthreads();  // B2

  {
    const u32 b0 = (u32)t * 8u;
    u32 loc[8]; u32 lsum = 0;
    #pragma unroll
    for (int k = 0; k < 8; ++k) { loc[k] = h1[b0 + k]; lsum += loc[k]; }
    u32 s = lsum;
    #pragma unroll
    for (int off = 1; off < 64; off <<= 1) {
      u32 v = __shfl_down(s, off, 64);
      if (lane + off < 64) s += v;
    }
    if (lane == 0) wsum[wave] = s;
    __syncthreads();  // B3
    u32 aboveW = 0;
    #pragma unroll
    for (int w = 0; w < 16; ++w) if (w > wave) aboveW += wsum[w];
    u32 above = aboveW + (s - lsum);
    if (above < 100u && above + lsum >= 100u) {
      u32 acc = above;
      #pragma unroll
      for (int k = 7; k >= 0; --k) {
        acc += loc[k];
        if (acc >= 100u) { sPref = b0 + (u32)k; sT2 = 100u - (acc - loc[k]); break; }
      }
    }
    __syncthreads();  // B4
  }
  const u32 pref = sPref, rt = sT2;

  for (int i = t; i < 8000; i += 1024) {
    u32 b = vals[i];
    u32 bin = b >> 17; if (bin > 8191u) bin = 8191u;
    if (bin == pref) atomicAdd(&h2[(b >> 3) & 0x3FFFu], 1u);
  }
  __syncthreads();  // B5

  {
    const u32 b0 = (u32)t * 16u;
    u32 loc[16]; u32 lsum = 0;
    #pragma unroll
    for (int k = 0; k < 16; ++k) { loc[k] = h2[b0 + k]; lsum += loc[k]; }
    u32 s = lsum;
    #pragma unroll
    for (int off = 1; off < 64; off <<= 1) {
      u32 v = __shfl_down(s, off, 64);
      if (lane + off < 64) s += v;
    }
    if (lane == 0) wsum[wave] = s;
    __syncthreads();  // B6
    u32 aboveW = 0;
    #pragma unroll
    for (int w = 0; w < 16; ++w) if (w > wave) aboveW += wsum[w];
    u32 above = aboveW + (s - lsum);
    if (above < rt && above + lsum >= rt) {
      u32 acc = above;
      #pragma unroll
      for (int k = 15; k >= 0; --k) {
        acc += loc[k];
        if (acc >= rt) { sThr = (pref << 17) | ((b0 + (u32)k) << 3); break; }
      }
    }
    __syncthreads();  // B7
  }
  const u32 thr = sThr;

  for (int i = t; i < 8000; i += 1024) {
    u32 v = vals[i];
    if (v >= thr) {
      u32 p = atomicAdd(&scnt, 1u);
      if (p < 512u) cands[p] = v;
    }
  }
  __syncthreads();  // B8
  const u32 nc = scnt;

  if (nc <= 512u) {
    if (wave == 0) {
      for (int k = 2; k <= 512; k <<= 1)
        for (int j = k >> 1; j > 0; j >>= 1) {
          for (int p = lane; p < 256; p += 64) {
            int i  = ((p & ~(j - 1)) << 1) | (p & (j - 1));
            int ix = i | j;
            bool up = (i & k) == 0;
            u32 a = cands[i], b = cands[ix];
            if (up ? (a < b) : (a > b)) { cands[i] = b; cands[ix] = a; }
          }
          __builtin_amdgcn_wave_barrier();
        }
      out[lane] = __uint_as_float(cands[lane]);
      if (lane < 36) out[lane + 64] = __uint_as_float(cands[lane + 64]);
    }
  } else {
    for (int i = t; i < 8192; i += 1024) h2[i] = (i < 8000) ? vals[i] : 0u;
    __syncthreads();
    for (int k = 2; k <= 8192; k <<= 1)
      for (int j = k >> 1; j > 0; j >>= 1) {
        for (int p = t; p < 4096; p += 1024) {
          int i  = ((p & ~(j - 1)) << 1) | (p & (j - 1));
          int ix = i | j;
          bool up = (i & k) == 0;
          u32 a = h2[i], b = h2[ix];
          if (up ? (a < b) : (a > b)) { h2[i] = b; h2[ix] = a; }
        }
        __syncthreads();
      }
    if (t < 100) out[t] = __uint_as_float(h2[t]);
  }
}

extern "C" void kernel_launch(void* const* d_in, const int* in_sizes, int n_in,
                              void* d_out, int out_size, void* d_ws, size_t ws_size,
                              hipStream_t stream) {
  const float* scores = (const float*)d_in[0];
  const float* boxes  = (const float*)d_in[1];
  float* out = (float*)d_out;
  char* ws = (char*)d_ws;

  u32* T16     = (u32*)(ws + OFF_T16);
  u32* T160    = (u32*)(ws + OFF_T160);
  u32* cnt     = (u32*)(ws + OFF_CNT);
  float* cls_out = (float*)(ws + OFF_CLSOUT);
  u32* ghistA  = (u32*)(ws + OFF_GHA);
  u32* ghistB  = (u32*)(ws + OFF_GHB);
  u64* cand    = (u64*)(ws + OFF_CAND);
  u32* bcnt    = (u32*)(ws + OFF_BCNT);

  k_zero<<<30, 256, 0, stream>>>(ghistA);  // zeros ghistA+ghistB (contiguous)
  k_histA<<<NBLK, 256, 0, stream>>>(scores, ghistA);
  k_histB_f<<<NBLK, 256, 0, stream>>>(scores, ghistA, ghistB);
  k_count_f<<<NBLK, 256, 0, stream>>>(scores, ghistA, ghistB, T16, T160, cnt, bcnt);
  k_place_f<<<NBLK, 256, 0, stream>>>(scores, T16, bcnt, cand);
  k_sortnms<<<N_CLS, 256, 0, stream>>>(cand, cnt, T160, boxes, cls_out);
  k_final<<<1, 1024, 0, stream>>>(cls_out, out);
}